// Round 3
// baseline (20410.422 us; speedup 1.0000x reference)
//
#include <hip/hip_runtime.h>
#include <stdint.h>

// Must match numpy float32 rounding exactly: (dx*dx + dy*dy) + dz*dz, no FMA.
#pragma clang fp contract(off)

#define NPT      2048
#define NBATCH   32
#define NPTS     65536
#define MEMBERS  8
#define NTHREADS 1024
#define CHUNK    (NPTS / MEMBERS)          // 8192 points per block
#define PPT      (CHUNK / NTHREADS)        // 8 points per thread
#define WPB      (NTHREADS / 64)           // 16 waves per block
#define SLOTS    (MEMBERS * WPB)           // 128 wave-slots per batch

__device__ __forceinline__ uint32_t f2u(float f) { return __float_as_uint(f); }
__device__ __forceinline__ float u2f(uint32_t u) { return __uint_as_float(u); }

// One block per CU (256 blocks), 16 waves each. No __syncthreads anywhere:
// waves are independent publishers/consumers of tagged 64-bit slots.
__global__ void __launch_bounds__(NTHREADS, 4)
__attribute__((amdgpu_waves_per_eu(4, 4)))
fps_kernel(const float* __restrict__ xyz, int* __restrict__ out,
           uint64_t* __restrict__ cand)
{
    // Swizzle so a batch's 8 member blocks share blockIdx%8 (same-XCD heuristic).
    const int i = blockIdx.x;
    const int q = i >> 3;
    const int batch  = (i & 7) * 4 + (q & 3);   // [0,32)
    const int member = q >> 2;                  // [0,8)
    const int tid  = threadIdx.x;
    const int lane = tid & 63;
    const int wv   = tid >> 6;

    const float* xb = xyz + (size_t)batch * 3 * NPTS;
    const int idx0 = member * CHUNK + tid;

    // 32 data floats per thread -> comfortably arch-VGPR at the 128-reg cap.
    float px[PPT], py[PPT], pz[PPT], pd[PPT];
#pragma unroll
    for (int k = 0; k < PPT; ++k) {
        int p = idx0 + k * NTHREADS;
        px[k] = xb[p];
        py[k] = xb[NPTS + p];
        pz[k] = xb[2 * NPTS + p];
        pd[k] = 1e10f;
    }

    // First centroid is point 0; first emitted index is 0.
    float cx = xb[0], cy = xb[NPTS], cz = xb[2 * NPTS];
    if (member == 0 && tid == 0) out[(size_t)batch * NPT] = 0;

    uint64_t* cb = cand + (size_t)batch * 2 * SLOTS;  // [parity][SLOTS]
    const int sid = member * WPB + wv;                // this wave's slot [0,128)

    for (int t = 0; t < NPT - 1; ++t) {
        // ---- dist update + per-thread argmax (strict >, ascending k =
        //      ascending global index -> first-occurrence semantics) ----
        float bv = -1.0f;            // all dists >= 0, so always beaten
        int   bi = 0;
#pragma unroll
        for (int k = 0; k < PPT; ++k) {
            float dx = px[k] - cx;
            float dy = py[k] - cy;
            float dz = pz[k] - cz;
            float d  = dx * dx + dy * dy;   // contract(off): mul,mul,add
            d = d + dz * dz;                // then add — matches numpy order
            float nd = fminf(pd[k], d);
            pd[k] = nd;
            bool g = nd > bv;
            bv = g ? nd : bv;
            bi = g ? (idx0 + k * NTHREADS) : bi;
        }

        // ---- wave argmax-reduce (larger value wins; tie -> smaller index) ----
#pragma unroll
        for (int off = 1; off < 64; off <<= 1) {
            float ov = __shfl_xor(bv, off, 64);
            int   oi = __shfl_xor(bi, off, 64);
            if (ov > bv || (ov == bv && oi < bi)) { bv = ov; bi = oi; }
        }

        // ---- publish this wave's best as one tagged 64-bit word ----
        uint64_t* sb = cb + (size_t)(t & 1) * SLOTS;
        const uint32_t tag = (uint32_t)t;
        if (lane == 0) {
            uint64_t w = ((uint64_t)f2u(bv) << 32) | ((uint32_t)bi << 16) | tag;
            __hip_atomic_store(&sb[sid], w, __ATOMIC_RELAXED, __HIP_MEMORY_SCOPE_AGENT);
        }

        // ---- all lanes poll the 128 slots (2 per lane), relaxed agent loads ----
        uint64_t w0 = 0, w1 = 0;
        bool d0 = false, d1 = false;
        do {
            if (!d0) { w0 = __hip_atomic_load(&sb[lane],      __ATOMIC_RELAXED, __HIP_MEMORY_SCOPE_AGENT); d0 = (uint32_t)(w0 & 0xFFFF) == tag; }
            if (!d1) { w1 = __hip_atomic_load(&sb[lane + 64], __ATOMIC_RELAXED, __HIP_MEMORY_SCOPE_AGENT); d1 = (uint32_t)(w1 & 0xFFFF) == tag; }
        } while (!(d0 && d1));

        float v0 = u2f((uint32_t)(w0 >> 32)); int i0 = (int)((w0 >> 16) & 0xFFFF);
        float v1 = u2f((uint32_t)(w1 >> 32)); int i1 = (int)((w1 >> 16) & 0xFFFF);
        if (v1 > v0 || (v1 == v0 && i1 < i0)) { v0 = v1; i0 = i1; }

        // ---- global argmax-reduce across the wave -> every lane has winner ----
#pragma unroll
        for (int off = 1; off < 64; off <<= 1) {
            float ov = __shfl_xor(v0, off, 64);
            int   oi = __shfl_xor(i0, off, 64);
            if (ov > v0 || (ov == v0 && oi < i0)) { v0 = ov; i0 = oi; }
        }

        // new centroid (uniform index; read-only data, L1/L2-cached)
        cx = xb[i0];
        cy = xb[NPTS + i0];
        cz = xb[2 * NPTS + i0];
        if (member == 0 && tid == 0) out[(size_t)batch * NPT + t + 1] = i0;
    }
}

extern "C" void kernel_launch(void* const* d_in, const int* in_sizes, int n_in,
                              void* d_out, int out_size, void* d_ws, size_t ws_size,
                              hipStream_t stream)
{
    const float* xyz = (const float*)d_in[0];
    int* out = (int*)d_out;
    uint64_t* cand = (uint64_t*)d_ws;   // 32*2*128*8 = 64 KiB used
    // No memset needed: slots are iteration-tagged and leftover tags
    // (0xAAAA poison or 2045/2046 from a previous replay) never match the
    // polled tag before being overwritten by this launch's writes.
    fps_kernel<<<NBATCH * MEMBERS, NTHREADS, 0, stream>>>(xyz, out, cand);
}

// Round 4
// 5323.032 us; speedup vs baseline: 3.8344x; 3.8344x over previous
//
#include <hip/hip_runtime.h>
#include <stdint.h>

// Must match numpy float32 rounding exactly: (dx*dx + dy*dy) + dz*dz, no FMA.
#pragma clang fp contract(off)

#define NPT      2048
#define NBATCH   32
#define NPTS     65536
#define MEMBERS  8
#define NTHREADS 512
#define CHUNK    (NPTS / MEMBERS)       // 8192 points per block
#define PPT      (CHUNK / NTHREADS)     // 16 points per thread
#define WPB      (NTHREADS / 64)        // 8 waves per block

__device__ __forceinline__ uint32_t f2u(float f) { return __float_as_uint(f); }
__device__ __forceinline__ float u2f(uint32_t u) { return __uint_as_float(u); }

__global__ void __launch_bounds__(NTHREADS)
fps_kernel(const float* __restrict__ xyz, int* __restrict__ out,
           uint64_t* __restrict__ cand)
{
    // x-coords in LDS purely as register-pressure relief: each thread writes
    // and later reads ONLY its own 16 slots (p = tid + k*512) -> no barriers
    // needed for sx, and consecutive lanes are 4B apart -> conflict-free.
    __shared__ float    sx[CHUNK];        // 32 KB
    __shared__ uint32_t red[WPB][2];
    __shared__ uint32_t bc[3];

    // Swizzle: a batch's 8 member blocks share blockIdx%8 (same-XCD heuristic;
    // correctness never depends on placement).
    const int i = blockIdx.x;
    const int q = i >> 3;
    const int batch  = (i & 7) * 4 + (q & 3);   // [0,32)
    const int member = q >> 2;                  // [0,8)
    const int tid  = threadIdx.x;
    const int lane = tid & 63;
    const int wv   = tid >> 6;

    const float* xb = xyz + (size_t)batch * 3 * NPTS;
    const int gbase = member * CHUNK;

    float py[PPT], pz[PPT], pd[PPT];    // 48 data VGPRs
#pragma unroll
    for (int k = 0; k < PPT; ++k) {
        int p = tid + k * NTHREADS;
        int g = gbase + p;
        sx[p] = xb[g];
        py[k] = xb[NPTS + g];
        pz[k] = xb[2 * NPTS + g];
        pd[k] = 1e10f;
    }

    // First centroid is point 0; first emitted index is 0.
    float cx = xb[0], cy = xb[NPTS], cz = xb[2 * NPTS];
    if (member == 0 && tid == 0) out[(size_t)batch * NPT] = 0;

    // cand[batch][parity][member]: one 64B line per (batch,parity).
    uint64_t* cb = cand + (size_t)batch * 2 * MEMBERS;

    for (int t = 0; t < NPT - 1; ++t) {
        // ---- dist update + per-thread argmax (strict >, ascending k =
        //      ascending global index -> first-occurrence semantics) ----
        float bv = -1.0f;            // all dists >= 0, so always beaten
        int   bi = 0;
#pragma unroll
        for (int k = 0; k < PPT; ++k) {
            int p = tid + k * NTHREADS;
            float dx = sx[p] - cx;
            float dy = py[k] - cy;
            float dz = pz[k] - cz;
            float d  = dx * dx + dy * dy;   // contract(off): mul,mul,add
            d = d + dz * dz;                // then add — matches numpy order
            float nd = fminf(pd[k], d);
            pd[k] = nd;
            bool g = nd > bv;
            bv = g ? nd : bv;
            bi = g ? (gbase + p) : bi;
        }

        // ---- wave argmax-reduce (larger wins; tie -> smaller index) ----
#pragma unroll
        for (int off = 1; off < 64; off <<= 1) {
            float ov = __shfl_xor(bv, off, 64);
            int   oi = __shfl_xor(bi, off, 64);
            if (ov > bv || (ov == bv && oi < bi)) { bv = ov; bi = oi; }
        }
        if (lane == 0) { red[wv][0] = f2u(bv); red[wv][1] = (uint32_t)bi; }
        __syncthreads();

        if (wv == 0) {
            // cross-wave reduce (lanes 0..7 hold the 8 wave-bests)
            float v = -1.0f; int ix = 0;
            if (lane < WPB) { v = u2f(red[lane][0]); ix = (int)red[lane][1]; }
#pragma unroll
            for (int off = 4; off >= 1; off >>= 1) {
                float ov = __shfl_xor(v, off, 64);
                int   oi = __shfl_xor(ix, off, 64);
                if (ov > v || (ov == v && oi < ix)) { v = ov; ix = oi; }
            }

            // ---- publish block-best as one tagged relaxed 64-bit word ----
            // ABA-safe: tag strictly increases; parity slot t is overwritten at
            // t+2 only after every block published t+1, which requires having
            // read all of t. Poison (0xAAAA) / stale tags (2045/2046 from a
            // previous replay) never match the polled tag -> no memset needed.
            uint64_t* sb = cb + (size_t)(t & 1) * MEMBERS;
            const uint32_t tag = (uint32_t)t;
            if (lane == 0) {
                uint64_t w = ((uint64_t)f2u(v) << 32)
                           | (uint64_t)((uint32_t)ix << 16) | tag;
                __hip_atomic_store(&sb[member], w, __ATOMIC_RELAXED,
                                   __HIP_MEMORY_SCOPE_AGENT);
            }

            // ---- poll the 8 slots (one 64B line; lane l watches slot l&7) ----
            uint64_t w = 0; bool done = false;
            do {
                if (!done) w = __hip_atomic_load(&sb[lane & 7], __ATOMIC_RELAXED,
                                                 __HIP_MEMORY_SCOPE_AGENT);
                done = (uint32_t)(w & 0xFFFFu) == tag;
            } while (!__all(done));

            float gv = u2f((uint32_t)(w >> 32));
            int   gi = (int)((w >> 16) & 0xFFFFu);
#pragma unroll
            for (int off = 1; off < 8; off <<= 1) {
                float ov = __shfl_xor(gv, off, 64);
                int   oi = __shfl_xor(gi, off, 64);
                if (ov > gv || (ov == gv && oi < gi)) { gv = ov; gi = oi; }
            }

            // winner coords (read-only global, cached) + output index
            if (lane < 3) bc[lane] = f2u(xb[(size_t)lane * NPTS + gi]);
            if (lane == 0 && member == 0) out[(size_t)batch * NPT + t + 1] = gi;
        }
        __syncthreads();
        cx = u2f(bc[0]); cy = u2f(bc[1]); cz = u2f(bc[2]);
    }
}

extern "C" void kernel_launch(void* const* d_in, const int* in_sizes, int n_in,
                              void* d_out, int out_size, void* d_ws, size_t ws_size,
                              hipStream_t stream)
{
    const float* xyz = (const float*)d_in[0];
    int* out = (int*)d_out;
    uint64_t* cand = (uint64_t*)d_ws;   // 32*2*8*8 = 4 KiB used; no memset needed
    fps_kernel<<<NBATCH * MEMBERS, NTHREADS, 0, stream>>>(xyz, out, cand);
}